// Round 2
// baseline (295.489 us; speedup 1.0000x reference)
//
#include <hip/hip_runtime.h>
#include <hip/hip_bf16.h>
#include <math.h>

#define NLAT 255
#define LMAX 96
#define MMAX 96
#define BC   256
#define NPIX 49152

// ---------------- ring geometry (NSIDE=64, compile-time closed forms) -------
__device__ __forceinline__ void ring_params(int t, int& n, int& roff) {
    if (t < 63)        { n = 4 * (t + 1); roff = 2 * t * (t + 1); }
    else if (t <= 191) { n = 256;         roff = 8064 + 256 * (t - 63); }
    else               { int w = 255 - t; n = 4 * w; roff = 49152 - 2 * w * (w + 1); }
}

// ---------------- kernel 1: transpose x[bc][l][m] -> xT[m][l][bc] -----------
__global__ __launch_bounds__(256) void k_transpose(
        const float* __restrict__ xr, const float* __restrict__ xi,
        float* __restrict__ xTr, float* __restrict__ xTi) {
    __shared__ float tile[32][33];
    const int l   = blockIdx.x;          // 0..95
    const int bc0 = blockIdx.y * 32;     // 0..224
    const int z   = blockIdx.z;          // 0..5
    const int comp = z / 3;
    const int m0   = (z % 3) * 32;
    const float* in  = comp ? xi : xr;
    float*       out = comp ? xTi : xTr;
    const int tx = threadIdx.x;          // 0..31
    const int ty = threadIdx.y;          // 0..7
#pragma unroll
    for (int j = 0; j < 4; ++j) {
        int bcl = ty + j * 8;
        tile[bcl][tx] = in[((bc0 + bcl) * 96 + l) * 96 + m0 + tx];
    }
    __syncthreads();
#pragma unroll
    for (int j = 0; j < 4; ++j) {
        int ml = ty + j * 8;
        out[((m0 + ml) * 96 + l) * 256 + bc0 + tx] = tile[tx][ml];
    }
}

// ---------------- kernel 2: Legendre contraction + phase --------------------
// X[t][m][bc] (interleaved re,im as float2) = e^{i off[t,m]} * sum_l pct[m,l,t] * x[bc,l,m]
// pct values are wave-uniform -> read straight from global (scalar s_load path),
// NO LDS staging.
__global__ __launch_bounds__(256) void k_legendre(
        const float* __restrict__ xTr, const float* __restrict__ xTi,
        const float* __restrict__ pct, const float* __restrict__ off,
        float2* __restrict__ X) {
    const int m  = blockIdx.x;        // 0..95
    const int t0 = blockIdx.y * 32;   // 0..224
    const int tid = threadIdx.x;      // bc
    const int tmax = 254 - t0;        // clamp (only matters for t0==224)

    float accR[32], accI[32];
#pragma unroll
    for (int i = 0; i < 32; ++i) { accR[i] = 0.f; accI[i] = 0.f; }

    const float* __restrict__ pbase = pct + (m * 96) * NLAT + t0;  // [l][tt], l-stride NLAT
    const float* __restrict__ xrB = xTr + (m * 96) * 256 + tid;
    const float* __restrict__ xiB = xTi + (m * 96) * 256 + tid;

    for (int l = 0; l < 96; ++l) {
        float xr = xrB[l * 256];
        float xi = xiB[l * 256];
        const float* __restrict__ prow = pbase + l * NLAT;
#pragma unroll
        for (int tt = 0; tt < 32; ++tt) {
            float p = prow[tt <= tmax ? tt : tmax];   // uniform scalar load
            accR[tt] = fmaf(p, xr, accR[tt]);
            accI[tt] = fmaf(p, xi, accI[tt]);
        }
    }

#pragma unroll
    for (int tt = 0; tt < 32; ++tt) {
        int t = t0 + tt;
        if (t < NLAT) {
            float o = off[t * 96 + m];
            float so, co;
            __sincosf(o, &so, &co);
            float r = accR[tt] * co - accI[tt] * so;
            float i = accR[tt] * so + accI[tt] * co;
            X[(t * 96 + m) * 256 + tid] = make_float2(r, i);
        }
    }
}

// ---------------- kernel 3: per-ring direct inverse real DFT ----------------
// y[p] = sum_{m=0}^{min(95, n/2)} scale_m * (Xr cos(2pi m p/n) - Xi sin(2pi m p/n))
// scale_m = 1 for m=0 and m=n/2 (DC/Nyquist, imag dropped via s=0), else 2.
// X values are wave-uniform -> global scalar loads, no LDS. Twiddles per-thread
// via complex rotation recurrence; scale folded into the twiddle.
__global__ __launch_bounds__(256) void k_dft(
        const float2* __restrict__ X, float* __restrict__ out) {
    const int t   = blockIdx.x;        // 0..254
    const int bc0 = blockIdx.y * 32;   // bc tile
    const int p   = threadIdx.x;

    int n, roff;
    ring_params(t, n, roff);
    if (p >= n) return;                // whole trailing waves retire immediately
    const int half = n >> 1;
    const int mtop = min(95, half);

    float delta = (float)p * (6.28318530717958647692f / (float)n);
    float cd, sd;
    __sincosf(delta, &sd, &cd);
    float c = 1.f, s = 0.f;

    float y[32];
#pragma unroll
    for (int b = 0; b < 32; ++b) y[b] = 0.f;

    const float2* __restrict__ Xrow = X + (t * 96) * 256 + bc0;   // [m][b]

    for (int m = 0; m <= mtop; ++m) {
        float sc = (m == 0 || m == half) ? 1.f : 2.f;
        float cc = c * sc;
        float ns = -s * sc;
#pragma unroll
        for (int b = 0; b < 32; ++b) {
            float2 v = Xrow[b];        // uniform scalar load (s_load_dwordx*)
            y[b] = fmaf(v.x, cc, y[b]);
            y[b] = fmaf(v.y, ns, y[b]);
        }
        Xrow += 256;
        float cn = c * cd - s * sd;
        s = s * cd + c * sd;
        c = cn;
    }

    const int base = roff + p;
#pragma unroll
    for (int b = 0; b < 32; ++b) {
        out[(bc0 + b) * NPIX + base] = y[b];
    }
}

// ---------------- launcher --------------------------------------------------
extern "C" void kernel_launch(void* const* d_in, const int* in_sizes, int n_in,
                              void* d_out, int out_size, void* d_ws, size_t ws_size,
                              hipStream_t stream) {
    const float* xr  = (const float*)d_in[0];   // (4,64,96,96)
    const float* xi  = (const float*)d_in[1];   // (4,64,96,96)
    const float* pct = (const float*)d_in[2];   // (96,96,255)
    const float* off = (const float*)d_in[3];   // (255,96)
    float* out = (float*)d_out;                 // (4,64,49152)

    float* ws  = (float*)d_ws;
    float* xTr = ws;                        // 96*96*256 floats
    float* xTi = ws + 2359296;              // 96*96*256 floats
    float2* X  = (float2*)(ws + 4718592);   // 255*96*256 float2

    k_transpose<<<dim3(96, 8, 6), dim3(32, 8), 0, stream>>>(xr, xi, xTr, xTi);
    k_legendre<<<dim3(96, 8), 256, 0, stream>>>(xTr, xTi, pct, off, X);
    k_dft<<<dim3(NLAT, 8), 256, 0, stream>>>(X, out);
}